// Round 1
// baseline (44.831 us; speedup 1.0000x reference)
//
#include <hip/hip_runtime.h>

typedef short bf16x8 __attribute__((ext_vector_type(8)));
typedef float f32x4 __attribute__((ext_vector_type(4)));

#define MFMA16(A, B, C) __builtin_amdgcn_mfma_f32_16x16x32_bf16((A), (B), (C), 0, 0, 0)

static __device__ __forceinline__ ushort f2bf(float f) {
    unsigned u = __builtin_bit_cast(unsigned, f);
    unsigned r = (u + 0x7FFFu + ((u >> 16) & 1u)) >> 16;
    return (ushort)r;
}
static __device__ __forceinline__ float bf2f(ushort h) {
    return __builtin_bit_cast(float, ((unsigned)h) << 16);
}
static __device__ __forceinline__ unsigned pk2(float a, float b) {
    return (unsigned)f2bf(a) | ((unsigned)f2bf(b) << 16);
}
static __device__ __forceinline__ bf16x8 ldg8(const ushort* p) {
    uint4 u = *(const uint4*)p;
    return __builtin_bit_cast(bf16x8, u);
}

// ---- workspace layout (bytes) ----
// qT_hi: [2][48*48][512] bf16              @ 0        size 4718592
// qT_lo:                                   @ 4718592  size 4718592
// kT_hi: [2][24][32pad][512] bf16          @ 9437184  size 1572864
// kT_lo:                                   @ 11010048 size 1572864
// v4   : [4][2][512][25][32pad] bf16       @ 12582912 size 6553600
// total 19136512
#define OFF_QHI 0
#define OFF_QLO 4718592
#define OFF_KHI 9437184
#define OFF_KLO 11010048
#define OFF_V4  12582912
#define WS_NEED 19136512

// q (2,512,48,48) f32 -> qT hi/lo bf16 [2][2304][512], transposed via LDS tile
__global__ __launch_bounds__(256) void prep_q(const float* __restrict__ q,
                                              ushort* __restrict__ qhi,
                                              ushort* __restrict__ qlo) {
    __shared__ float tile[32][33];
    int bid = blockIdx.x;
    int b = bid / 1152;
    int rem = bid % 1152;
    int p0 = (rem / 16) * 32;
    int c0 = (rem % 16) * 32;
    int tx = threadIdx.x & 31, tw = threadIdx.x >> 5;
#pragma unroll
    for (int i = 0; i < 4; ++i) {
        int r = tw + i * 8;
        tile[r][tx] = q[(size_t)(b * 512 + c0 + r) * 2304 + p0 + tx];
    }
    __syncthreads();
#pragma unroll
    for (int i = 0; i < 4; ++i) {
        int r = tw + i * 8;
        float v = tile[tx][r];
        ushort hi = f2bf(v);
        ushort lo = f2bf(v - bf2f(hi));
        size_t idx = (size_t)(b * 2304 + p0 + r) * 512 + c0 + tx;
        qhi[idx] = hi;
        qlo[idx] = lo;
    }
}

// k (2,512,24,24) f32 -> kT hi/lo bf16 [2][24][32pad][512]
__global__ __launch_bounds__(256) void prep_k(const float* __restrict__ k,
                                              ushort* __restrict__ khi,
                                              ushort* __restrict__ klo) {
    __shared__ float tile[32][33];
    int bid = blockIdx.x;
    int b = bid / 288;
    int rem = bid % 288;
    int p0 = (rem / 16) * 32;
    int c0 = (rem % 16) * 32;
    int tx = threadIdx.x & 31, tw = threadIdx.x >> 5;
#pragma unroll
    for (int i = 0; i < 4; ++i) {
        int r = tw + i * 8;
        tile[r][tx] = k[(size_t)(b * 512 + c0 + r) * 576 + p0 + tx];
    }
    __syncthreads();
#pragma unroll
    for (int i = 0; i < 4; ++i) {
        int r = tw + i * 8;
        int pix = p0 + r;
        int kr = pix / 24, kc = pix % 24;
        float v = tile[tx][r];
        ushort hi = f2bf(v);
        ushort lo = f2bf(v - bf2f(hi));
        size_t idx = ((size_t)(b * 24 + kr) * 32 + kc) * 512 + c0 + tx;
        khi[idx] = hi;
        klo[idx] = lo;
    }
}

// v (2,512,24,24) f32 -> 4 column-shifted bf16 copies [s][2][512][25][32]
__global__ __launch_bounds__(256) void prep_v(const float* __restrict__ v,
                                              ushort* __restrict__ v4) {
    int t = blockIdx.x * 256 + threadIdx.x;  // grid covers exactly 589824
    int kc = t % 24;
    int kr = (t / 24) % 24;
    int c = (t / 576) % 512;
    int b = t / (576 * 512);
    ushort hv = f2bf(v[t]);
#pragma unroll
    for (int s = 0; s < 4; ++s) {
        int col = kc - 2 * s;
        if (col >= 0) {
            v4[((size_t)((s * 2 + b) * 512 + c) * 25 + kr) * 32 + col] = hv;
        }
    }
}

// One wave per (2x8 pixel tile, head). 2304 blocks x 64 threads.
__global__ __launch_bounds__(64) void attn(const ushort* __restrict__ qhi,
                                           const ushort* __restrict__ qlo,
                                           const ushort* __restrict__ khi,
                                           const ushort* __restrict__ klo,
                                           const ushort* __restrict__ v4,
                                           float* __restrict__ out) {
    __shared__ __align__(16) unsigned Plds[16][84];  // [pixel][160 taps as bf16 pairs, stride 84]

    int bid = blockIdx.x;
    int h = bid & 7;
    int t = bid >> 3;
    int tx = t % 6;
    int tyb = t / 6;  // 0..47
    int ty = tyb % 24;
    int b = tyb / 24;

    int l = threadIdx.x;
    int pix = l & 15, g = l >> 4;
    int px = pix & 7, py = pix >> 3;
    int y = ty * 2 + py, x = tx * 8 + px;

    int sr = min(max(ty - 4, 0), 15);            // shared row start (all 16 pixels)
    int sw0 = min(max(4 * tx - 4, 0), 15);       // col start of first pixel
    int swe = sw0 & ~1;                          // even base of col-union
    int sw = min(max((x >> 1) - 4, 0), 15);      // this pixel's col start
    int dx = sw - swe;                           // 0..4: valid tap cols = [dx, dx+8]
    int s2 = swe & 6, scopy = s2 >> 1, colbase = swe - s2;  // colbase in {0,8}

    // Q fragments (B-operand: col=pixel, k = g*8.. per kstep), hi+lo
    const int qoff = ((b * 2304 + y * 48 + x) << 9) + h * 64 + g * 8;
    bf16x8 qh0 = ldg8(qhi + qoff), qh1 = ldg8(qhi + qoff + 32);
    bf16x8 ql0 = ldg8(qlo + qoff), ql1 = ldg8(qlo + qoff + 32);

    // QK^T (swapped): S^T[tap][pixel], 9 mtiles of 16 taps (tap = m*16 + tc)
    f32x4 sc[9];
#pragma unroll
    for (int m = 0; m < 9; ++m) {
        int koff = (((b * 24 + sr + m) << 5) + swe + pix) * 512 + h * 64 + g * 8;
        bf16x8 kh0 = ldg8(khi + koff), kh1 = ldg8(khi + koff + 32);
        bf16x8 kl0 = ldg8(klo + koff), kl1 = ldg8(klo + koff + 32);
        f32x4 a = {0.f, 0.f, 0.f, 0.f};
        a = MFMA16(kh0, qh0, a);
        a = MFMA16(kh1, qh1, a);
        a = MFMA16(kl0, qh0, a);
        a = MFMA16(kh0, ql0, a);
        a = MFMA16(kl1, qh1, a);
        a = MFMA16(kh1, ql1, a);
        sc[m] = a;
    }

    // masked softmax over taps; lane holds tap cols tc = g*4+r for all 9 rows
    const float C2 = 0.18033688011112042f;  // 0.125 * log2(e)
    float mx = -3.0e38f;
#pragma unroll
    for (int r = 0; r < 4; ++r) {
        if ((unsigned)(g * 4 + r - dx) <= 8u) {
#pragma unroll
            for (int m = 0; m < 9; ++m) mx = fmaxf(mx, sc[m][r]);
        }
    }
    mx = fmaxf(mx, __shfl_xor(mx, 16));
    mx = fmaxf(mx, __shfl_xor(mx, 32));
    float sum = 0.f;
#pragma unroll
    for (int m = 0; m < 9; ++m) {
#pragma unroll
        for (int r = 0; r < 4; ++r) {
            bool valid = (unsigned)(g * 4 + r - dx) <= 8u;
            float p = valid ? exp2f((sc[m][r] - mx) * C2) : 0.f;
            sc[m][r] = p;
            sum += p;
        }
    }
    sum += __shfl_xor(sum, 16);
    sum += __shfl_xor(sum, 32);

    // P -> LDS (bf16), layout [pixel][tap] so PV B-frag reads are contiguous 16B
#pragma unroll
    for (int m = 0; m < 9; ++m) {
        uint2 w;
        w.x = pk2(sc[m][0], sc[m][1]);
        w.y = pk2(sc[m][2], sc[m][3]);
        *(uint2*)&Plds[pix][m * 8 + g * 2] = w;
    }
    *(uint2*)&Plds[pix][72 + g * 2] = make_uint2(0u, 0u);  // taps 144..159 = 0

    // PV (swapped): out^T[d][pixel] = V^T (A) x P^T (B), K = 160 taps
    f32x4 o[4] = {{0.f, 0.f, 0.f, 0.f}, {0.f, 0.f, 0.f, 0.f}, {0.f, 0.f, 0.f, 0.f}, {0.f, 0.f, 0.f, 0.f}};
#pragma unroll
    for (int ks = 0; ks < 5; ++ks) {
        uint4 pw = *(const uint4*)&Plds[pix][ks * 16 + g * 4];
        bf16x8 pf = __builtin_bit_cast(bf16x8, pw);
        int tap0 = ks * 32 + g * 8;
        int tr = tap0 >> 4, tc0 = tap0 & 15;
#pragma unroll
        for (int md = 0; md < 4; ++md) {
            int c = h * 64 + md * 16 + pix;
            const ushort* vp = v4 + ((size_t)((scopy * 2 + b) * 512 + c) * 25 + sr + tr) * 32 + colbase + tc0;
            o[md] = MFMA16(ldg8(vp), pf, o[md]);
        }
    }

    float invd = 1.0f / sum;
#pragma unroll
    for (int md = 0; md < 4; ++md) {
#pragma unroll
        for (int r = 0; r < 4; ++r) {
            int d = md * 16 + g * 4 + r;
            out[((size_t)(b * 512 + h * 64 + d) * 48 + y) * 48 + x] = o[md][r] * invd;
        }
    }
}

extern "C" void kernel_launch(void* const* d_in, const int* in_sizes, int n_in,
                              void* d_out, int out_size, void* d_ws, size_t ws_size,
                              hipStream_t stream) {
    const float* q = (const float*)d_in[0];
    const float* k = (const float*)d_in[1];
    const float* v = (const float*)d_in[2];
    float* out = (float*)d_out;
    char* ws = (char*)d_ws;
    if (ws_size < (size_t)WS_NEED) return;

    ushort* qhi = (ushort*)(ws + OFF_QHI);
    ushort* qlo = (ushort*)(ws + OFF_QLO);
    ushort* khi = (ushort*)(ws + OFF_KHI);
    ushort* klo = (ushort*)(ws + OFF_KLO);
    ushort* v4 = (ushort*)(ws + OFF_V4);

    // zero the padded K / V regions every launch (deterministic)
    hipMemsetAsync(ws + OFF_KHI, 0, WS_NEED - OFF_KHI, stream);
    prep_q<<<2304, 256, 0, stream>>>(q, qhi, qlo);
    prep_k<<<576, 256, 0, stream>>>(k, khi, klo);
    prep_v<<<2304, 256, 0, stream>>>(v, v4);
    attn<<<2304, 64, 0, stream>>>(qhi, qlo, khi, klo, v4, out);
}

// Round 2
// 34.809 us; speedup vs baseline: 1.2879x; 1.2879x over previous
//
#include <hip/hip_runtime.h>

typedef short bf16x8 __attribute__((ext_vector_type(8)));
typedef float f32x4 __attribute__((ext_vector_type(4)));
typedef ushort u16x8 __attribute__((ext_vector_type(8)));

#define MFMA16(A, B, C) __builtin_amdgcn_mfma_f32_16x16x32_bf16((A), (B), (C), 0, 0, 0)

static __device__ __forceinline__ ushort f2bf(float f) {
    unsigned u = __builtin_bit_cast(unsigned, f);
    unsigned r = (u + 0x7FFFu + ((u >> 16) & 1u)) >> 16;
    return (ushort)r;
}
static __device__ __forceinline__ float bf2f(ushort h) {
    return __builtin_bit_cast(float, ((unsigned)h) << 16);
}
static __device__ __forceinline__ unsigned pk2(float a, float b) {
    return (unsigned)f2bf(a) | ((unsigned)f2bf(b) << 16);
}
static __device__ __forceinline__ bf16x8 ldg8(const ushort* p) {
    uint4 u = *(const uint4*)p;
    return __builtin_bit_cast(bf16x8, u);
}

// ---- workspace layout (bytes) ----
// qT_hi: [2][48*48][512] bf16              @ 0        size 4718592
// qT_lo:                                   @ 4718592  size 4718592
// kT_hi: [2][24][32pad][512] bf16          @ 9437184  size 1572864
// kT_lo:                                   @ 11010048 size 1572864
// v4   : [4][2][512][25][32pad] bf16       @ 12582912 size 6553600
// total 19136512
#define OFF_QHI 0
#define OFF_QLO 4718592
#define OFF_KHI 9437184
#define OFF_KLO 11010048
#define OFF_V4  12582912
#define WS_NEED 19136512

// Fused prep:
//   blocks [0, 2304)      : q (2,512,48,48) f32 -> qT hi/lo bf16 [2][2304][512]
//   blocks [2304, 2880)   : k (2,512,24,24) f32 -> kT hi/lo bf16 [2][24][32pad][512]
//   blocks [2880, 4480)   : v (2,512,24,24) f32 -> v4 gather [4][2][512][25][32pad]
//                           (writes EVERY element incl. zeros -> replaces memset)
__global__ __launch_bounds__(256) void prep(const float* __restrict__ q,
                                            const float* __restrict__ k,
                                            const float* __restrict__ v,
                                            ushort* __restrict__ qhi,
                                            ushort* __restrict__ qlo,
                                            ushort* __restrict__ khi,
                                            ushort* __restrict__ klo,
                                            ushort* __restrict__ v4) {
    __shared__ float tile[32][33];
    int bid = blockIdx.x;

    if (bid < 2304) {
        // ---- Q transpose + hi/lo split ----
        int b = bid / 1152;
        int rem = bid % 1152;
        int p0 = (rem / 16) * 32;
        int c0 = (rem % 16) * 32;
        int tx = threadIdx.x & 31, tw = threadIdx.x >> 5;
#pragma unroll
        for (int i = 0; i < 4; ++i) {
            int r = tw + i * 8;
            tile[r][tx] = q[(size_t)(b * 512 + c0 + r) * 2304 + p0 + tx];
        }
        __syncthreads();
#pragma unroll
        for (int i = 0; i < 4; ++i) {
            int r = tw + i * 8;
            float val = tile[tx][r];
            ushort hi = f2bf(val);
            ushort lo = f2bf(val - bf2f(hi));
            size_t idx = (size_t)(b * 2304 + p0 + r) * 512 + c0 + tx;
            qhi[idx] = hi;
            qlo[idx] = lo;
        }
    } else if (bid < 2880) {
        // ---- K transpose + hi/lo split (pad cols 24..31 left unwritten:
        //      their scores land only at softmax-masked tap positions) ----
        int kbid = bid - 2304;
        int b = kbid / 288;
        int rem = kbid % 288;
        int p0 = (rem / 16) * 32;
        int c0 = (rem % 16) * 32;
        int tx = threadIdx.x & 31, tw = threadIdx.x >> 5;
#pragma unroll
        for (int i = 0; i < 4; ++i) {
            int r = tw + i * 8;
            tile[r][tx] = k[(size_t)(b * 512 + c0 + r) * 576 + p0 + tx];
        }
        __syncthreads();
#pragma unroll
        for (int i = 0; i < 4; ++i) {
            int r = tw + i * 8;
            int pix = p0 + r;
            int kr = pix / 24, kc = pix % 24;
            float val = tile[tx][r];
            ushort hi = f2bf(val);
            ushort lo = f2bf(val - bf2f(hi));
            size_t idx = ((size_t)(b * 24 + kr) * 32 + kc) * 512 + c0 + tx;
            khi[idx] = hi;
            klo[idx] = lo;
        }
    } else {
        // ---- V gather: 4 column-shifted bf16 copies, zeros in all padding ----
        // element layout: (((s*2+b)*512+c)*25+kr)*32+col ; thread -> 8 cols
        int tid = (bid - 2880) * 256 + threadIdx.x;  // 409600 threads total
        int col0 = (tid & 3) * 8;
        int rowlin = tid >> 2;
        int kr = rowlin % 25;
        int c = (rowlin / 25) % 512;
        int b = (rowlin / (25 * 512)) & 1;
        int s = rowlin / (25 * 512 * 2);
        const float* src = v + (size_t)(b * 512 + c) * 576 + kr * 24;
        u16x8 w;
#pragma unroll
        for (int j = 0; j < 8; ++j) {
            int srcc = col0 + j + 2 * s;
            w[j] = (kr < 24 && srcc < 24) ? f2bf(src[srcc]) : (ushort)0;
        }
        *(u16x8*)&v4[(size_t)rowlin * 32 + col0] = w;
    }
}

// One wave per (2x8 pixel tile, head). 2304 blocks x 64 threads.
__global__ __launch_bounds__(64) void attn(const ushort* __restrict__ qhi,
                                           const ushort* __restrict__ qlo,
                                           const ushort* __restrict__ khi,
                                           const ushort* __restrict__ klo,
                                           const ushort* __restrict__ v4,
                                           float* __restrict__ out) {
    __shared__ __align__(16) unsigned Plds[16][84];  // [pixel][160 taps as bf16 pairs, stride 84]

    int bid = blockIdx.x;
    int h = bid & 7;
    int t = bid >> 3;
    int tx = t % 6;
    int tyb = t / 6;  // 0..47
    int ty = tyb % 24;
    int b = tyb / 24;

    int l = threadIdx.x;
    int pix = l & 15, g = l >> 4;
    int px = pix & 7, py = pix >> 3;
    int y = ty * 2 + py, x = tx * 8 + px;

    int sr = min(max(ty - 4, 0), 15);            // shared row start (all 16 pixels)
    int sw0 = min(max(4 * tx - 4, 0), 15);       // col start of first pixel
    int swe = sw0 & ~1;                          // even base of col-union
    int sw = min(max((x >> 1) - 4, 0), 15);      // this pixel's col start
    int dx = sw - swe;                           // 0..4: valid tap cols = [dx, dx+8]
    int s2 = swe & 6, scopy = s2 >> 1, colbase = swe - s2;  // colbase in {0,8}

    // Q fragments (B-operand: col=pixel, k = g*8.. per kstep), hi+lo
    const int qoff = ((b * 2304 + y * 48 + x) << 9) + h * 64 + g * 8;
    bf16x8 qh0 = ldg8(qhi + qoff), qh1 = ldg8(qhi + qoff + 32);
    bf16x8 ql0 = ldg8(qlo + qoff), ql1 = ldg8(qlo + qoff + 32);

    // QK^T (swapped): S^T[tap][pixel], 9 mtiles of 16 taps (tap = m*16 + tc)
    f32x4 sc[9];
#pragma unroll
    for (int m = 0; m < 9; ++m) {
        int koff = (((b * 24 + sr + m) << 5) + swe + pix) * 512 + h * 64 + g * 8;
        bf16x8 kh0 = ldg8(khi + koff), kh1 = ldg8(khi + koff + 32);
        bf16x8 kl0 = ldg8(klo + koff), kl1 = ldg8(klo + koff + 32);
        f32x4 a = {0.f, 0.f, 0.f, 0.f};
        a = MFMA16(kh0, qh0, a);
        a = MFMA16(kh1, qh1, a);
        a = MFMA16(kl0, qh0, a);
        a = MFMA16(kh0, ql0, a);
        a = MFMA16(kl1, qh1, a);
        a = MFMA16(kh1, ql1, a);
        sc[m] = a;
    }

    // masked softmax over taps; lane holds tap cols tc = g*4+r for all 9 rows
    const float C2 = 0.18033688011112042f;  // 0.125 * log2(e)
    float mx = -3.0e38f;
#pragma unroll
    for (int r = 0; r < 4; ++r) {
        if ((unsigned)(g * 4 + r - dx) <= 8u) {
#pragma unroll
            for (int m = 0; m < 9; ++m) mx = fmaxf(mx, sc[m][r]);
        }
    }
    mx = fmaxf(mx, __shfl_xor(mx, 16));
    mx = fmaxf(mx, __shfl_xor(mx, 32));
    float sum = 0.f;
#pragma unroll
    for (int m = 0; m < 9; ++m) {
#pragma unroll
        for (int r = 0; r < 4; ++r) {
            bool valid = (unsigned)(g * 4 + r - dx) <= 8u;
            float p = valid ? exp2f((sc[m][r] - mx) * C2) : 0.f;
            sc[m][r] = p;
            sum += p;
        }
    }
    sum += __shfl_xor(sum, 16);
    sum += __shfl_xor(sum, 32);

    // P -> LDS (bf16), layout [pixel][tap] so PV B-frag reads are contiguous 16B
#pragma unroll
    for (int m = 0; m < 9; ++m) {
        uint2 w;
        w.x = pk2(sc[m][0], sc[m][1]);
        w.y = pk2(sc[m][2], sc[m][3]);
        *(uint2*)&Plds[pix][m * 8 + g * 2] = w;
    }
    *(uint2*)&Plds[pix][72 + g * 2] = make_uint2(0u, 0u);  // taps 144..159 = 0

    // PV (swapped): out^T[d][pixel] = V^T (A) x P^T (B), K = 160 taps
    f32x4 o[4] = {{0.f, 0.f, 0.f, 0.f}, {0.f, 0.f, 0.f, 0.f}, {0.f, 0.f, 0.f, 0.f}, {0.f, 0.f, 0.f, 0.f}};
#pragma unroll
    for (int ks = 0; ks < 5; ++ks) {
        uint4 pw = *(const uint4*)&Plds[pix][ks * 16 + g * 4];
        bf16x8 pf = __builtin_bit_cast(bf16x8, pw);
        int tap0 = ks * 32 + g * 8;
        int tr = tap0 >> 4, tc0 = tap0 & 15;
#pragma unroll
        for (int md = 0; md < 4; ++md) {
            int c = h * 64 + md * 16 + pix;
            const ushort* vp = v4 + ((size_t)((scopy * 2 + b) * 512 + c) * 25 + sr + tr) * 32 + colbase + tc0;
            o[md] = MFMA16(ldg8(vp), pf, o[md]);
        }
    }

    float invd = 1.0f / sum;
#pragma unroll
    for (int md = 0; md < 4; ++md) {
#pragma unroll
        for (int r = 0; r < 4; ++r) {
            int d = md * 16 + g * 4 + r;
            out[((size_t)(b * 512 + h * 64 + d) * 48 + y) * 48 + x] = o[md][r] * invd;
        }
    }
}

extern "C" void kernel_launch(void* const* d_in, const int* in_sizes, int n_in,
                              void* d_out, int out_size, void* d_ws, size_t ws_size,
                              hipStream_t stream) {
    const float* q = (const float*)d_in[0];
    const float* k = (const float*)d_in[1];
    const float* v = (const float*)d_in[2];
    float* out = (float*)d_out;
    char* ws = (char*)d_ws;
    if (ws_size < (size_t)WS_NEED) return;

    ushort* qhi = (ushort*)(ws + OFF_QHI);
    ushort* qlo = (ushort*)(ws + OFF_QLO);
    ushort* khi = (ushort*)(ws + OFF_KHI);
    ushort* klo = (ushort*)(ws + OFF_KLO);
    ushort* v4 = (ushort*)(ws + OFF_V4);

    prep<<<4480, 256, 0, stream>>>(q, k, v, qhi, qlo, khi, klo, v4);
    attn<<<2304, 64, 0, stream>>>(qhi, qlo, khi, klo, v4, out);
}

// Round 3
// 25.582 us; speedup vs baseline: 1.7525x; 1.3607x over previous
//
#include <hip/hip_runtime.h>

typedef short bf16x8 __attribute__((ext_vector_type(8)));
typedef float f32x4 __attribute__((ext_vector_type(4)));
typedef ushort u16x8 __attribute__((ext_vector_type(8)));

#define MFMA16(A, B, C) __builtin_amdgcn_mfma_f32_16x16x32_bf16((A), (B), (C), 0, 0, 0)

static __device__ __forceinline__ ushort f2bf(float f) {
    unsigned u = __builtin_bit_cast(unsigned, f);
    unsigned r = (u + 0x7FFFu + ((u >> 16) & 1u)) >> 16;
    return (ushort)r;
}
static __device__ __forceinline__ unsigned pk2(float a, float b) {
    return (unsigned)f2bf(a) | ((unsigned)f2bf(b) << 16);
}
static __device__ __forceinline__ bf16x8 ldg8(const ushort* p) {
    uint4 u = *(const uint4*)p;
    return __builtin_bit_cast(bf16x8, u);
}

// ---- workspace layout (bytes) ----
// qT : [2][48*48][512] bf16                @ 0        size 4718592
// kT : [2][24][32pad][512] bf16            @ 4718592  size 1572864
// v4 : [4][2][512][25][32pad] bf16         @ 6291456  size 6553600
// total 12845056
#define OFF_QT 0
#define OFF_KT 4718592
#define OFF_V4 6291456
#define WS_NEED 12845056

// Fused prep:
//   blocks [0, 2304)      : q (2,512,48,48) f32 -> qT bf16 [2][2304][512]
//   blocks [2304, 2880)   : k (2,512,24,24) f32 -> kT bf16 [2][24][32pad][512]
//                           (pad cols 24..31 left unwritten: only feed
//                            softmax-masked tap positions, values irrelevant)
//   blocks [2880, 4480)   : v (2,512,24,24) f32 -> v4 gather [4][2][512][25][32pad]
//                           (writes EVERY element incl. zeros -> no memset)
__global__ __launch_bounds__(256) void prep(const float* __restrict__ q,
                                            const float* __restrict__ k,
                                            const float* __restrict__ v,
                                            ushort* __restrict__ qt,
                                            ushort* __restrict__ kt,
                                            ushort* __restrict__ v4) {
    __shared__ float tile[32][33];
    int bid = blockIdx.x;

    if (bid < 2304) {
        // ---- Q transpose -> bf16 ----
        int b = bid / 1152;
        int rem = bid % 1152;
        int p0 = (rem / 16) * 32;
        int c0 = (rem % 16) * 32;
        int tx = threadIdx.x & 31, tw = threadIdx.x >> 5;
#pragma unroll
        for (int i = 0; i < 4; ++i) {
            int r = tw + i * 8;
            tile[r][tx] = q[(size_t)(b * 512 + c0 + r) * 2304 + p0 + tx];
        }
        __syncthreads();
#pragma unroll
        for (int i = 0; i < 4; ++i) {
            int r = tw + i * 8;
            qt[(size_t)(b * 2304 + p0 + r) * 512 + c0 + tx] = f2bf(tile[tx][r]);
        }
    } else if (bid < 2880) {
        // ---- K transpose -> bf16 ----
        int kbid = bid - 2304;
        int b = kbid / 288;
        int rem = kbid % 288;
        int p0 = (rem / 16) * 32;
        int c0 = (rem % 16) * 32;
        int tx = threadIdx.x & 31, tw = threadIdx.x >> 5;
#pragma unroll
        for (int i = 0; i < 4; ++i) {
            int r = tw + i * 8;
            tile[r][tx] = k[(size_t)(b * 512 + c0 + r) * 576 + p0 + tx];
        }
        __syncthreads();
#pragma unroll
        for (int i = 0; i < 4; ++i) {
            int r = tw + i * 8;
            int pix = p0 + r;
            int kr = pix / 24, kc = pix % 24;
            kt[((size_t)(b * 24 + kr) * 32 + kc) * 512 + c0 + tx] = f2bf(tile[tx][r]);
        }
    } else {
        // ---- V gather: 4 column-shifted bf16 copies, zeros in all padding ----
        int tid = (bid - 2880) * 256 + threadIdx.x;  // 409600 threads total
        int col0 = (tid & 3) * 8;
        int rowlin = tid >> 2;
        int kr = rowlin % 25;
        int c = (rowlin / 25) % 512;
        int b = (rowlin / (25 * 512)) & 1;
        int s = rowlin / (25 * 512 * 2);
        const float* src = v + (size_t)(b * 512 + c) * 576 + kr * 24;
        u16x8 w;
#pragma unroll
        for (int j = 0; j < 8; ++j) {
            int srcc = col0 + j + 2 * s;
            w[j] = (kr < 24 && srcc < 24) ? f2bf(src[srcc]) : (ushort)0;
        }
        *(u16x8*)&v4[(size_t)rowlin * 32 + col0] = w;
    }
}

// One wave per (2x8 pixel tile, head). 2304 blocks x 64 threads.
__global__ __launch_bounds__(64) void attn(const ushort* __restrict__ qt,
                                           const ushort* __restrict__ kt,
                                           const ushort* __restrict__ v4,
                                           float* __restrict__ out) {
    __shared__ __align__(16) unsigned Plds[16][84];  // [pixel][160 taps as bf16 pairs, stride 84]

    int bid = blockIdx.x;
    int h = bid & 7;
    int t = bid >> 3;
    int tx = t % 6;
    int tyb = t / 6;  // 0..47
    int ty = tyb % 24;
    int b = tyb / 24;

    int l = threadIdx.x;
    int pix = l & 15, g = l >> 4;
    int px = pix & 7, py = pix >> 3;
    int y = ty * 2 + py, x = tx * 8 + px;

    int sr = min(max(ty - 4, 0), 15);            // shared row start (all 16 pixels)
    int sw0 = min(max(4 * tx - 4, 0), 15);       // col start of first pixel
    int swe = sw0 & ~1;                          // even base of col-union
    int sw = min(max((x >> 1) - 4, 0), 15);      // this pixel's col start
    int dx = sw - swe;                           // 0..4: valid tap cols = [dx, dx+8]
    int s2 = swe & 6, scopy = s2 >> 1, colbase = swe - s2;  // colbase in {0,8}

    // Q fragments (B-operand: col=pixel, k = g*8.. per kstep)
    const int qoff = ((b * 2304 + y * 48 + x) << 9) + h * 64 + g * 8;
    bf16x8 q0 = ldg8(qt + qoff), q1 = ldg8(qt + qoff + 32);

    // QK^T (swapped): S^T[tap][pixel], 9 mtiles of 16 taps
    f32x4 sc[9];
#pragma unroll
    for (int m = 0; m < 9; ++m) {
        int koff = (((b * 24 + sr + m) << 5) + swe + pix) * 512 + h * 64 + g * 8;
        bf16x8 k0 = ldg8(kt + koff), k1 = ldg8(kt + koff + 32);
        f32x4 a = {0.f, 0.f, 0.f, 0.f};
        a = MFMA16(k0, q0, a);
        a = MFMA16(k1, q1, a);
        sc[m] = a;
    }

    // masked softmax over taps; lane holds tap cols tc = g*4+r for all 9 rows
    const float C2 = 0.18033688011112042f;  // 0.125 * log2(e)
    float mx = -3.0e38f;
#pragma unroll
    for (int r = 0; r < 4; ++r) {
        if ((unsigned)(g * 4 + r - dx) <= 8u) {
#pragma unroll
            for (int m = 0; m < 9; ++m) mx = fmaxf(mx, sc[m][r]);
        }
    }
    mx = fmaxf(mx, __shfl_xor(mx, 16));
    mx = fmaxf(mx, __shfl_xor(mx, 32));
    float sum = 0.f;
#pragma unroll
    for (int m = 0; m < 9; ++m) {
#pragma unroll
        for (int r = 0; r < 4; ++r) {
            bool valid = (unsigned)(g * 4 + r - dx) <= 8u;
            float p = valid ? exp2f((sc[m][r] - mx) * C2) : 0.f;
            sc[m][r] = p;
            sum += p;
        }
    }
    sum += __shfl_xor(sum, 16);
    sum += __shfl_xor(sum, 32);

    // P -> LDS (bf16), layout [pixel][tap] so PV B-frag reads are contiguous 16B
#pragma unroll
    for (int m = 0; m < 9; ++m) {
        uint2 w;
        w.x = pk2(sc[m][0], sc[m][1]);
        w.y = pk2(sc[m][2], sc[m][3]);
        *(uint2*)&Plds[pix][m * 8 + g * 2] = w;
    }
    *(uint2*)&Plds[pix][72 + g * 2] = make_uint2(0u, 0u);  // taps 144..159 = 0

    // PV (swapped): out^T[d][pixel] = V^T (A) x P^T (B), K = 160 taps
    f32x4 o[4] = {{0.f, 0.f, 0.f, 0.f}, {0.f, 0.f, 0.f, 0.f}, {0.f, 0.f, 0.f, 0.f}, {0.f, 0.f, 0.f, 0.f}};
#pragma unroll
    for (int ks = 0; ks < 5; ++ks) {
        uint4 pw = *(const uint4*)&Plds[pix][ks * 16 + g * 4];
        bf16x8 pf = __builtin_bit_cast(bf16x8, pw);
        int tap0 = ks * 32 + g * 8;
        int tr = tap0 >> 4, tc0 = tap0 & 15;
#pragma unroll
        for (int md = 0; md < 4; ++md) {
            int c = h * 64 + md * 16 + pix;
            const ushort* vp = v4 + ((size_t)((scopy * 2 + b) * 512 + c) * 25 + sr + tr) * 32 + colbase + tc0;
            o[md] = MFMA16(ldg8(vp), pf, o[md]);
        }
    }

    float invd = 1.0f / sum;
#pragma unroll
    for (int md = 0; md < 4; ++md) {
#pragma unroll
        for (int r = 0; r < 4; ++r) {
            int d = md * 16 + g * 4 + r;
            out[((size_t)(b * 512 + h * 64 + d) * 48 + y) * 48 + x] = o[md][r] * invd;
        }
    }
}

extern "C" void kernel_launch(void* const* d_in, const int* in_sizes, int n_in,
                              void* d_out, int out_size, void* d_ws, size_t ws_size,
                              hipStream_t stream) {
    const float* q = (const float*)d_in[0];
    const float* k = (const float*)d_in[1];
    const float* v = (const float*)d_in[2];
    float* out = (float*)d_out;
    char* ws = (char*)d_ws;
    if (ws_size < (size_t)WS_NEED) return;

    ushort* qt = (ushort*)(ws + OFF_QT);
    ushort* kt = (ushort*)(ws + OFF_KT);
    ushort* v4 = (ushort*)(ws + OFF_V4);

    prep<<<4480, 256, 0, stream>>>(q, k, v, qt, kt, v4);
    attn<<<2304, 64, 0, stream>>>(qt, kt, v4, out);
}

// Round 4
// 23.945 us; speedup vs baseline: 1.8723x; 1.0684x over previous
//
#include <hip/hip_runtime.h>

typedef short bf16x8 __attribute__((ext_vector_type(8)));
typedef float f32x4 __attribute__((ext_vector_type(4)));
typedef ushort u16x8 __attribute__((ext_vector_type(8)));

#define MFMA16(A, B, C) __builtin_amdgcn_mfma_f32_16x16x32_bf16((A), (B), (C), 0, 0, 0)

static __device__ __forceinline__ ushort f2bf(float f) {
    unsigned u = __builtin_bit_cast(unsigned, f);
    unsigned r = (u + 0x7FFFu + ((u >> 16) & 1u)) >> 16;
    return (ushort)r;
}
static __device__ __forceinline__ unsigned pk2(float a, float b) {
    return (unsigned)f2bf(a) | ((unsigned)f2bf(b) << 16);
}
static __device__ __forceinline__ bf16x8 ldg8(const ushort* p) {
    uint4 u = *(const uint4*)p;
    return __builtin_bit_cast(bf16x8, u);
}

// ---- workspace layout (bytes) ----
// kT : [2][24][32pad][512] bf16            @ 0        size 1572864
// v4 : [4][2][512][25][32pad] bf16         @ 1572864  size 6553600
// total 8126464   (Q is consumed directly from f32 by attn — no transpose copy)
#define OFF_KT 0
#define OFF_V4 1572864
#define WS_NEED 8126464

// Fused K/V prep:
//   blocks [0, 576)     : k (2,512,24,24) f32 -> kT bf16 [2][24][32pad][512]
//                         (pad cols 24..31 left unwritten: they only feed
//                          softmax-masked tap positions, values irrelevant)
//   blocks [576, 2176)  : v (2,512,24,24) f32 -> v4 gather [4][2][512][25][32pad]
//                         (writes EVERY element incl. zeros -> no memset needed)
__global__ __launch_bounds__(256) void prep(const float* __restrict__ k,
                                            const float* __restrict__ v,
                                            ushort* __restrict__ kt,
                                            ushort* __restrict__ v4) {
    __shared__ float tile[32][33];
    int bid = blockIdx.x;

    if (bid < 576) {
        // ---- K transpose -> bf16 ----
        int b = bid / 288;
        int rem = bid % 288;
        int p0 = (rem / 16) * 32;
        int c0 = (rem % 16) * 32;
        int tx = threadIdx.x & 31, tw = threadIdx.x >> 5;
#pragma unroll
        for (int i = 0; i < 4; ++i) {
            int r = tw + i * 8;
            tile[r][tx] = k[(size_t)(b * 512 + c0 + r) * 576 + p0 + tx];
        }
        __syncthreads();
#pragma unroll
        for (int i = 0; i < 4; ++i) {
            int r = tw + i * 8;
            int pix = p0 + r;
            int kr = pix / 24, kc = pix % 24;
            kt[((size_t)(b * 24 + kr) * 32 + kc) * 512 + c0 + tx] = f2bf(tile[tx][r]);
        }
    } else {
        // ---- V gather: 4 column-shifted bf16 copies, zeros in all padding ----
        int tid = (bid - 576) * 256 + threadIdx.x;  // 409600 threads total
        int col0 = (tid & 3) * 8;
        int rowlin = tid >> 2;
        int kr = rowlin % 25;
        int c = (rowlin / 25) % 512;
        int b = (rowlin / (25 * 512)) & 1;
        int s = rowlin / (25 * 512 * 2);
        const float* src = v + (size_t)(b * 512 + c) * 576 + kr * 24;
        u16x8 w;
#pragma unroll
        for (int j = 0; j < 8; ++j) {
            int srcc = col0 + j + 2 * s;
            w[j] = (kr < 24 && srcc < 24) ? f2bf(src[srcc]) : (ushort)0;
        }
        *(u16x8*)&v4[(size_t)rowlin * 32 + col0] = w;
    }
}

// One wave per (2x8 pixel tile, head). 2304 blocks x 64 threads.
// Q is gathered directly from the original f32 layout (each element used once).
__global__ __launch_bounds__(64) void attn(const float* __restrict__ q,
                                           const ushort* __restrict__ kt,
                                           const ushort* __restrict__ v4,
                                           float* __restrict__ out) {
    __shared__ __align__(16) unsigned Plds[16][84];  // [pixel][160 taps as bf16 pairs, stride 84]

    int bid = blockIdx.x;
    int h = bid & 7;
    int t = bid >> 3;
    int tx = t % 6;
    int tyb = t / 6;  // 0..47
    int ty = tyb % 24;
    int b = tyb / 24;

    int l = threadIdx.x;
    int pix = l & 15, g = l >> 4;
    int px = pix & 7, py = pix >> 3;
    int y = ty * 2 + py, x = tx * 8 + px;

    int sr = min(max(ty - 4, 0), 15);            // shared row start (all 16 pixels)
    int sw0 = min(max(4 * tx - 4, 0), 15);       // col start of first pixel
    int swe = sw0 & ~1;                          // even base of col-union
    int sw = min(max((x >> 1) - 4, 0), 15);      // this pixel's col start
    int dx = sw - swe;                           // 0..4: valid tap cols = [dx, dx+8]
    int s2 = swe & 6, scopy = s2 >> 1, colbase = swe - s2;  // colbase in {0,8}

    // Q fragments (B-operand: col=pixel, k = channel within head):
    // lane (g,pix) needs channels h*64 + g*8 + j (kstep 0) and +32 (kstep 1),
    // gathered straight from q[b][c][y][x] (stride 2304 between channels).
    const float* qsrc = q + (size_t)(b * 512 + h * 64 + g * 8) * 2304 + y * 48 + x;
    float t0[8], t1[8];
#pragma unroll
    for (int j = 0; j < 8; ++j) t0[j] = qsrc[(size_t)j * 2304];
#pragma unroll
    for (int j = 0; j < 8; ++j) t1[j] = qsrc[(size_t)(j + 32) * 2304];
    bf16x8 q0, q1;
#pragma unroll
    for (int j = 0; j < 8; ++j) {
        q0[j] = (short)f2bf(t0[j]);
        q1[j] = (short)f2bf(t1[j]);
    }

    // QK^T (swapped): S^T[tap][pixel], 9 mtiles of 16 taps
    f32x4 sc[9];
#pragma unroll
    for (int m = 0; m < 9; ++m) {
        int koff = (((b * 24 + sr + m) << 5) + swe + pix) * 512 + h * 64 + g * 8;
        bf16x8 k0 = ldg8(kt + koff), k1 = ldg8(kt + koff + 32);
        f32x4 a = {0.f, 0.f, 0.f, 0.f};
        a = MFMA16(k0, q0, a);
        a = MFMA16(k1, q1, a);
        sc[m] = a;
    }

    // masked softmax over taps; lane holds tap cols tc = g*4+r for all 9 rows
    const float C2 = 0.18033688011112042f;  // 0.125 * log2(e)
    float mx = -3.0e38f;
#pragma unroll
    for (int r = 0; r < 4; ++r) {
        if ((unsigned)(g * 4 + r - dx) <= 8u) {
#pragma unroll
            for (int m = 0; m < 9; ++m) mx = fmaxf(mx, sc[m][r]);
        }
    }
    mx = fmaxf(mx, __shfl_xor(mx, 16));
    mx = fmaxf(mx, __shfl_xor(mx, 32));
    float sum = 0.f;
#pragma unroll
    for (int m = 0; m < 9; ++m) {
#pragma unroll
        for (int r = 0; r < 4; ++r) {
            bool valid = (unsigned)(g * 4 + r - dx) <= 8u;
            float p = valid ? exp2f((sc[m][r] - mx) * C2) : 0.f;
            sc[m][r] = p;
            sum += p;
        }
    }
    sum += __shfl_xor(sum, 16);
    sum += __shfl_xor(sum, 32);

    // P -> LDS (bf16), layout [pixel][tap] so PV B-frag reads are contiguous 16B
#pragma unroll
    for (int m = 0; m < 9; ++m) {
        uint2 w;
        w.x = pk2(sc[m][0], sc[m][1]);
        w.y = pk2(sc[m][2], sc[m][3]);
        *(uint2*)&Plds[pix][m * 8 + g * 2] = w;
    }
    *(uint2*)&Plds[pix][72 + g * 2] = make_uint2(0u, 0u);  // taps 144..159 = 0

    // PV (swapped): out^T[d][pixel] = V^T (A) x P^T (B), K = 160 taps
    f32x4 o[4] = {{0.f, 0.f, 0.f, 0.f}, {0.f, 0.f, 0.f, 0.f}, {0.f, 0.f, 0.f, 0.f}, {0.f, 0.f, 0.f, 0.f}};
#pragma unroll
    for (int ks = 0; ks < 5; ++ks) {
        uint4 pw = *(const uint4*)&Plds[pix][ks * 16 + g * 4];
        bf16x8 pf = __builtin_bit_cast(bf16x8, pw);
        int tap0 = ks * 32 + g * 8;
        int tr = tap0 >> 4, tc0 = tap0 & 15;
#pragma unroll
        for (int md = 0; md < 4; ++md) {
            int c = h * 64 + md * 16 + pix;
            const ushort* vp = v4 + ((size_t)((scopy * 2 + b) * 512 + c) * 25 + sr + tr) * 32 + colbase + tc0;
            o[md] = MFMA16(ldg8(vp), pf, o[md]);
        }
    }

    float invd = 1.0f / sum;
#pragma unroll
    for (int md = 0; md < 4; ++md) {
#pragma unroll
        for (int r = 0; r < 4; ++r) {
            int d = md * 16 + g * 4 + r;
            out[((size_t)(b * 512 + h * 64 + d) * 48 + y) * 48 + x] = o[md][r] * invd;
        }
    }
}

extern "C" void kernel_launch(void* const* d_in, const int* in_sizes, int n_in,
                              void* d_out, int out_size, void* d_ws, size_t ws_size,
                              hipStream_t stream) {
    const float* q = (const float*)d_in[0];
    const float* k = (const float*)d_in[1];
    const float* v = (const float*)d_in[2];
    float* out = (float*)d_out;
    char* ws = (char*)d_ws;
    if (ws_size < (size_t)WS_NEED) return;

    ushort* kt = (ushort*)(ws + OFF_KT);
    ushort* v4 = (ushort*)(ws + OFF_V4);

    prep<<<2176, 256, 0, stream>>>(k, v, kt, v4);
    attn<<<2304, 64, 0, stream>>>(q, kt, v4, out);
}